// Round 1
// baseline (2970.074 us; speedup 1.0000x reference)
//
#include <hip/hip_runtime.h>
#include <hip/hip_bf16.h>

#define D_IN  32
#define D_EF  16
#define D_H   64
#define D_MSG 32
#define D_UP  32

// ---------------------------------------------------------------------------
// Kernel 1: per-node precompute of the message-MLP first-layer partials.
//   P1[n] = x[n] @ W1m[0:32, :]  + b1m   (consumed indexed by dst)
//   P2[n] = x[n] @ W1m[32:64, :]         (consumed indexed by src)
// ---------------------------------------------------------------------------
__global__ __launch_bounds__(256) void node_pre_kernel(
    const float* __restrict__ x,
    const float* __restrict__ W1m,
    const float* __restrict__ b1m,
    float* __restrict__ P1,
    float* __restrict__ P2,
    int n_nodes)
{
    int i = blockIdx.x * blockDim.x + threadIdx.x;
    if (i >= n_nodes) return;

    float xi[D_IN];
    const float4* xp = (const float4*)(x + (size_t)i * D_IN);
#pragma unroll
    for (int k4 = 0; k4 < D_IN / 4; ++k4) {
        float4 v = xp[k4];
        xi[4 * k4 + 0] = v.x; xi[4 * k4 + 1] = v.y;
        xi[4 * k4 + 2] = v.z; xi[4 * k4 + 3] = v.w;
    }

    // ---- P1 pass (rows 0..31 of W1m), bias folded in ----
    {
        float acc[D_H];
#pragma unroll
        for (int j = 0; j < D_H; ++j) acc[j] = b1m[j];
        for (int k = 0; k < D_IN; ++k) {
            float xv = xi[k];
            const float* wr = W1m + (size_t)k * D_H;
#pragma unroll
            for (int j = 0; j < D_H; ++j) acc[j] += xv * wr[j];
        }
        float4* o = (float4*)(P1 + (size_t)i * D_H);
#pragma unroll
        for (int j4 = 0; j4 < D_H / 4; ++j4)
            o[j4] = make_float4(acc[4 * j4], acc[4 * j4 + 1], acc[4 * j4 + 2], acc[4 * j4 + 3]);
    }
    // ---- P2 pass (rows 32..63 of W1m) ----
    {
        float acc[D_H];
#pragma unroll
        for (int j = 0; j < D_H; ++j) acc[j] = 0.0f;
        for (int k = 0; k < D_IN; ++k) {
            float xv = xi[k];
            const float* wr = W1m + (size_t)(k + D_IN) * D_H;
#pragma unroll
            for (int j = 0; j < D_H; ++j) acc[j] += xv * wr[j];
        }
        float4* o = (float4*)(P2 + (size_t)i * D_H);
#pragma unroll
        for (int j4 = 0; j4 < D_H / 4; ++j4)
            o[j4] = make_float4(acc[4 * j4], acc[4 * j4 + 1], acc[4 * j4 + 2], acc[4 * j4 + 3]);
    }
}

// ---------------------------------------------------------------------------
// Kernel 2: per-edge message computation + atomic aggregation.
//   h = P1[dst] + P2[src] + ef @ W1m[64:80, :]
//   msg = relu(h) @ W2m + b2m
//   agg[dst] += msg   (fp32 atomics)
// ---------------------------------------------------------------------------
__global__ __launch_bounds__(256) void edge_kernel(
    const float* __restrict__ ef,
    const float* __restrict__ W1m,     // full matrix; we use rows 64..79
    const float* __restrict__ W2m,
    const float* __restrict__ b2m,
    const int*   __restrict__ ei,      // [2, E] : row 0 = src, row 1 = dst
    const float* __restrict__ P1,
    const float* __restrict__ P2,
    float* __restrict__ agg,
    int n_edges)
{
    int e = blockIdx.x * blockDim.x + threadIdx.x;
    if (e >= n_edges) return;

    int s = ei[e];
    int d = ei[n_edges + e];

    // h = P1[dst] + P2[src]
    float h[D_H];
    const float4* p1 = (const float4*)(P1 + (size_t)d * D_H);
    const float4* p2 = (const float4*)(P2 + (size_t)s * D_H);
#pragma unroll
    for (int j4 = 0; j4 < D_H / 4; ++j4) {
        float4 a = p1[j4];
        float4 b = p2[j4];
        h[4 * j4 + 0] = a.x + b.x;
        h[4 * j4 + 1] = a.y + b.y;
        h[4 * j4 + 2] = a.z + b.z;
        h[4 * j4 + 3] = a.w + b.w;
    }

    // + ef @ W1m[64:80, :]
    float efr[D_EF];
    const float4* efp = (const float4*)(ef + (size_t)e * D_EF);
#pragma unroll
    for (int k4 = 0; k4 < D_EF / 4; ++k4) {
        float4 v = efp[k4];
        efr[4 * k4 + 0] = v.x; efr[4 * k4 + 1] = v.y;
        efr[4 * k4 + 2] = v.z; efr[4 * k4 + 3] = v.w;
    }
    const float* W1E = W1m + (size_t)(2 * D_IN) * D_H;
    for (int k = 0; k < D_EF; ++k) {
        float ev = efr[k];
        const float* wr = W1E + (size_t)k * D_H;
#pragma unroll
        for (int j = 0; j < D_H; ++j) h[j] += ev * wr[j];
    }

    // msg = relu(h) @ W2m + b2m
    float msg[D_MSG];
#pragma unroll
    for (int m = 0; m < D_MSG; ++m) msg[m] = b2m[m];
    for (int j = 0; j < D_H; ++j) {
        float t = h[j] > 0.0f ? h[j] : 0.0f;
        const float* wr = W2m + (size_t)j * D_MSG;
#pragma unroll
        for (int m = 0; m < D_MSG; ++m) msg[m] += t * wr[m];
    }

    // agg[dst] += msg
    float* ap = agg + (size_t)d * D_MSG;
#pragma unroll
    for (int m = 0; m < D_MSG; ++m) atomicAdd(ap + m, msg[m]);
}

// ---------------------------------------------------------------------------
// Kernel 3: per-node update MLP.
//   out = relu([x, agg] @ W1u + b1u) @ W2u + b2u
// ---------------------------------------------------------------------------
__global__ __launch_bounds__(256) void node_upd_kernel(
    const float* __restrict__ x,
    const float* __restrict__ agg,
    const float* __restrict__ W1u,
    const float* __restrict__ b1u,
    const float* __restrict__ W2u,
    const float* __restrict__ b2u,
    float* __restrict__ out,
    int n_nodes)
{
    int i = blockIdx.x * blockDim.x + threadIdx.x;
    if (i >= n_nodes) return;

    float in[D_IN + D_MSG];
    const float4* xp = (const float4*)(x + (size_t)i * D_IN);
#pragma unroll
    for (int k4 = 0; k4 < D_IN / 4; ++k4) {
        float4 v = xp[k4];
        in[4 * k4 + 0] = v.x; in[4 * k4 + 1] = v.y;
        in[4 * k4 + 2] = v.z; in[4 * k4 + 3] = v.w;
    }
    const float4* ap = (const float4*)(agg + (size_t)i * D_MSG);
#pragma unroll
    for (int k4 = 0; k4 < D_MSG / 4; ++k4) {
        float4 v = ap[k4];
        in[D_IN + 4 * k4 + 0] = v.x; in[D_IN + 4 * k4 + 1] = v.y;
        in[D_IN + 4 * k4 + 2] = v.z; in[D_IN + 4 * k4 + 3] = v.w;
    }

    float h[D_H];
#pragma unroll
    for (int j = 0; j < D_H; ++j) h[j] = b1u[j];
    for (int k = 0; k < D_IN + D_MSG; ++k) {
        float v = in[k];
        const float* wr = W1u + (size_t)k * D_H;
#pragma unroll
        for (int j = 0; j < D_H; ++j) h[j] += v * wr[j];
    }

    float o[D_UP];
#pragma unroll
    for (int m = 0; m < D_UP; ++m) o[m] = b2u[m];
    for (int j = 0; j < D_H; ++j) {
        float t = h[j] > 0.0f ? h[j] : 0.0f;
        const float* wr = W2u + (size_t)j * D_UP;
#pragma unroll
        for (int m = 0; m < D_UP; ++m) o[m] += t * wr[m];
    }

    float4* op = (float4*)(out + (size_t)i * D_UP);
#pragma unroll
    for (int m4 = 0; m4 < D_UP / 4; ++m4)
        op[m4] = make_float4(o[4 * m4], o[4 * m4 + 1], o[4 * m4 + 2], o[4 * m4 + 3]);
}

extern "C" void kernel_launch(void* const* d_in, const int* in_sizes, int n_in,
                              void* d_out, int out_size, void* d_ws, size_t ws_size,
                              hipStream_t stream) {
    const float* x    = (const float*)d_in[0];
    // d_in[1] = degrees — unused by the reference computation
    const float* ef   = (const float*)d_in[2];
    const float* W1m  = (const float*)d_in[3];
    const float* b1m  = (const float*)d_in[4];
    const float* W2m  = (const float*)d_in[5];
    const float* b2m  = (const float*)d_in[6];
    const float* W1u  = (const float*)d_in[7];
    const float* b1u  = (const float*)d_in[8];
    const float* W2u  = (const float*)d_in[9];
    const float* b2u  = (const float*)d_in[10];
    const int*   ei   = (const int*)d_in[11];

    const int n_nodes = in_sizes[0] / D_IN;      // 50000
    const int n_edges = in_sizes[11] / 2;        // 1600000

    float* out = (float*)d_out;

    // Workspace layout:
    //   agg : n_nodes * D_MSG floats  (6.4 MB)  -- must be zeroed each call
    //   P1  : n_nodes * D_H   floats  (12.8 MB)
    //   P2  : n_nodes * D_H   floats  (12.8 MB)
    float* agg = (float*)d_ws;
    float* P1  = agg + (size_t)n_nodes * D_MSG;
    float* P2  = P1  + (size_t)n_nodes * D_H;

    hipMemsetAsync(agg, 0, (size_t)n_nodes * D_MSG * sizeof(float), stream);

    {
        int blk = 256;
        int grid = (n_nodes + blk - 1) / blk;
        node_pre_kernel<<<grid, blk, 0, stream>>>(x, W1m, b1m, P1, P2, n_nodes);
    }
    {
        int blk = 256;
        int grid = (n_edges + blk - 1) / blk;
        edge_kernel<<<grid, blk, 0, stream>>>(ef, W1m, W2m, b2m, ei, P1, P2, agg, n_edges);
    }
    {
        int blk = 256;
        int grid = (n_nodes + blk - 1) / blk;
        node_upd_kernel<<<grid, blk, 0, stream>>>(x, agg, W1u, b1u, W2u, b2u, out, n_nodes);
    }
}

// Round 2
// 1202.199 us; speedup vs baseline: 2.4705x; 2.4705x over previous
//
#include <hip/hip_runtime.h>
#include <hip/hip_bf16.h>

#define D_IN  32
#define D_EF  16
#define D_H   64
#define D_MSG 32
#define D_UP  32

// ---------------------------------------------------------------------------
// Kernel 1: per-node precompute of the message-MLP first-layer partials.
//   P1[n] = x[n] @ W1m[0:32, :]  + b1m   (consumed indexed by dst)
//   P2[n] = x[n] @ W1m[32:64, :]         (consumed indexed by src)
// ---------------------------------------------------------------------------
__global__ __launch_bounds__(256) void node_pre_kernel(
    const float* __restrict__ x,
    const float* __restrict__ W1m,
    const float* __restrict__ b1m,
    float* __restrict__ P1,
    float* __restrict__ P2,
    int n_nodes)
{
    int i = blockIdx.x * blockDim.x + threadIdx.x;
    if (i >= n_nodes) return;

    float xi[D_IN];
    const float4* xp = (const float4*)(x + (size_t)i * D_IN);
#pragma unroll
    for (int k4 = 0; k4 < D_IN / 4; ++k4) {
        float4 v = xp[k4];
        xi[4 * k4 + 0] = v.x; xi[4 * k4 + 1] = v.y;
        xi[4 * k4 + 2] = v.z; xi[4 * k4 + 3] = v.w;
    }

    {
        float acc[D_H];
#pragma unroll
        for (int j = 0; j < D_H; ++j) acc[j] = b1m[j];
        for (int k = 0; k < D_IN; ++k) {
            float xv = xi[k];
            const float* wr = W1m + (size_t)k * D_H;
#pragma unroll
            for (int j = 0; j < D_H; ++j) acc[j] += xv * wr[j];
        }
        float4* o = (float4*)(P1 + (size_t)i * D_H);
#pragma unroll
        for (int j4 = 0; j4 < D_H / 4; ++j4)
            o[j4] = make_float4(acc[4 * j4], acc[4 * j4 + 1], acc[4 * j4 + 2], acc[4 * j4 + 3]);
    }
    {
        float acc[D_H];
#pragma unroll
        for (int j = 0; j < D_H; ++j) acc[j] = 0.0f;
        for (int k = 0; k < D_IN; ++k) {
            float xv = xi[k];
            const float* wr = W1m + (size_t)(k + D_IN) * D_H;
#pragma unroll
            for (int j = 0; j < D_H; ++j) acc[j] += xv * wr[j];
        }
        float4* o = (float4*)(P2 + (size_t)i * D_H);
#pragma unroll
        for (int j4 = 0; j4 < D_H / 4; ++j4)
            o[j4] = make_float4(acc[4 * j4], acc[4 * j4 + 1], acc[4 * j4 + 2], acc[4 * j4 + 3]);
    }
}

// ---------------------------------------------------------------------------
// CSR build: histogram -> scan -> scatter
// ---------------------------------------------------------------------------
__global__ __launch_bounds__(256) void hist_kernel(
    const int* __restrict__ ei, int* __restrict__ deg, int n_edges)
{
    int e = blockIdx.x * blockDim.x + threadIdx.x;
    if (e < n_edges) atomicAdd(&deg[ei[n_edges + e]], 1);
}

__global__ __launch_bounds__(1024) void scan_kernel(
    const int* __restrict__ deg,
    int* __restrict__ offs,
    int* __restrict__ cursor,
    int n_nodes)
{
    __shared__ int sdata[1024];
    int t = threadIdx.x;
    int C = (n_nodes + 1023) / 1024;
    int base = t * C;

    int local = 0;
    for (int i = 0; i < C; ++i) {
        int idx = base + i;
        if (idx < n_nodes) local += deg[idx];
    }
    sdata[t] = local;
    __syncthreads();
    for (int off = 1; off < 1024; off <<= 1) {
        int v = (t >= off) ? sdata[t - off] : 0;
        __syncthreads();
        sdata[t] += v;
        __syncthreads();
    }
    int run = (t > 0) ? sdata[t - 1] : 0;
    for (int i = 0; i < C; ++i) {
        int idx = base + i;
        if (idx < n_nodes) {
            offs[idx]   = run;
            cursor[idx] = run;
            run += deg[idx];
        }
    }
}

__global__ __launch_bounds__(256) void scatter_kernel(
    const int* __restrict__ ei,
    int* __restrict__ cursor,
    int* __restrict__ eidx,
    int n_edges)
{
    int e = blockIdx.x * blockDim.x + threadIdx.x;
    if (e < n_edges) {
        int d = ei[n_edges + e];
        int pos = atomicAdd(&cursor[d], 1);
        eidx[pos] = e;
    }
}

// ---------------------------------------------------------------------------
// Kernel: gather-aggregate with on-the-fly message compute. 8 threads/node.
//   agg[n] = sum_{e in bucket(n)} relu(P1[n] + P2[src(e)] + ef[e]@W1E) @ W2m
//   (per-edge b2m bias folded into node_upd as deg[n]*b2m)
// ---------------------------------------------------------------------------
__global__ __launch_bounds__(256) void gather_kernel(
    const float* __restrict__ ef,
    const float* __restrict__ W1m,
    const float* __restrict__ W2m,
    const int*   __restrict__ ei,
    const float* __restrict__ P1,
    const float* __restrict__ P2,
    const int*   __restrict__ deg,
    const int*   __restrict__ offs,
    const int*   __restrict__ eidx,
    float* __restrict__ agg,
    int n_nodes, int n_edges)
{
    int tid = blockIdx.x * blockDim.x + threadIdx.x;
    int n = tid >> 3;
    int t = tid & 7;
    if (n >= n_nodes) return;

    int start = offs[n];
    int dc    = deg[n];
    const float* W1E = W1m + (size_t)(2 * D_IN) * D_H;

    float msg[D_MSG];
#pragma unroll
    for (int m = 0; m < D_MSG; ++m) msg[m] = 0.0f;

    for (int i = start + t; i < start + dc; i += 8) {
        int e = eidx[i];
        int s = ei[e];

        float h[D_H];
        const float4* p1 = (const float4*)(P1 + (size_t)n * D_H);
        const float4* p2 = (const float4*)(P2 + (size_t)s * D_H);
#pragma unroll
        for (int j4 = 0; j4 < D_H / 4; ++j4) {
            float4 a = p1[j4];
            float4 b = p2[j4];
            h[4 * j4 + 0] = a.x + b.x;
            h[4 * j4 + 1] = a.y + b.y;
            h[4 * j4 + 2] = a.z + b.z;
            h[4 * j4 + 3] = a.w + b.w;
        }

        float efr[D_EF];
        const float4* efp = (const float4*)(ef + (size_t)e * D_EF);
#pragma unroll
        for (int k4 = 0; k4 < D_EF / 4; ++k4) {
            float4 v = efp[k4];
            efr[4 * k4 + 0] = v.x; efr[4 * k4 + 1] = v.y;
            efr[4 * k4 + 2] = v.z; efr[4 * k4 + 3] = v.w;
        }
        for (int k = 0; k < D_EF; ++k) {
            float ev = efr[k];
            const float* wr = W1E + (size_t)k * D_H;
#pragma unroll
            for (int j = 0; j < D_H; ++j) h[j] += ev * wr[j];
        }

        for (int j = 0; j < D_H; ++j) {
            float r = h[j] > 0.0f ? h[j] : 0.0f;
            const float* wr = W2m + (size_t)j * D_MSG;
#pragma unroll
            for (int m = 0; m < D_MSG; ++m) msg[m] += r * wr[m];
        }
    }

    // reduce partial msg across the node's 8 lanes (lanes 8k..8k+7)
#pragma unroll
    for (int m = 0; m < D_MSG; ++m) {
        float v = msg[m];
        v += __shfl_xor(v, 1, 8);
        v += __shfl_xor(v, 2, 8);
        v += __shfl_xor(v, 4, 8);
        msg[m] = v;
    }

    if (t == 0) {
        float4* ap = (float4*)(agg + (size_t)n * D_MSG);
#pragma unroll
        for (int m4 = 0; m4 < D_MSG / 4; ++m4)
            ap[m4] = make_float4(msg[4 * m4], msg[4 * m4 + 1],
                                 msg[4 * m4 + 2], msg[4 * m4 + 3]);
    }
}

// ---------------------------------------------------------------------------
// Kernel: per-node update MLP (adds deg[n]*b2m to agg on the fly).
//   out = relu([x, agg + deg*b2m] @ W1u + b1u) @ W2u + b2u
// ---------------------------------------------------------------------------
__global__ __launch_bounds__(256) void node_upd_kernel(
    const float* __restrict__ x,
    const float* __restrict__ agg,
    const int*   __restrict__ deg,
    const float* __restrict__ b2m,
    const float* __restrict__ W1u,
    const float* __restrict__ b1u,
    const float* __restrict__ W2u,
    const float* __restrict__ b2u,
    float* __restrict__ out,
    int n_nodes)
{
    int i = blockIdx.x * blockDim.x + threadIdx.x;
    if (i >= n_nodes) return;

    float in[D_IN + D_MSG];
    const float4* xp = (const float4*)(x + (size_t)i * D_IN);
#pragma unroll
    for (int k4 = 0; k4 < D_IN / 4; ++k4) {
        float4 v = xp[k4];
        in[4 * k4 + 0] = v.x; in[4 * k4 + 1] = v.y;
        in[4 * k4 + 2] = v.z; in[4 * k4 + 3] = v.w;
    }
    float dc = (float)deg[i];
    const float4* ap = (const float4*)(agg + (size_t)i * D_MSG);
#pragma unroll
    for (int k4 = 0; k4 < D_MSG / 4; ++k4) {
        float4 v = ap[k4];
        in[D_IN + 4 * k4 + 0] = v.x + dc * b2m[4 * k4 + 0];
        in[D_IN + 4 * k4 + 1] = v.y + dc * b2m[4 * k4 + 1];
        in[D_IN + 4 * k4 + 2] = v.z + dc * b2m[4 * k4 + 2];
        in[D_IN + 4 * k4 + 3] = v.w + dc * b2m[4 * k4 + 3];
    }

    float h[D_H];
#pragma unroll
    for (int j = 0; j < D_H; ++j) h[j] = b1u[j];
    for (int k = 0; k < D_IN + D_MSG; ++k) {
        float v = in[k];
        const float* wr = W1u + (size_t)k * D_H;
#pragma unroll
        for (int j = 0; j < D_H; ++j) h[j] += v * wr[j];
    }

    float o[D_UP];
#pragma unroll
    for (int m = 0; m < D_UP; ++m) o[m] = b2u[m];
    for (int j = 0; j < D_H; ++j) {
        float r = h[j] > 0.0f ? h[j] : 0.0f;
        const float* wr = W2u + (size_t)j * D_UP;
#pragma unroll
        for (int m = 0; m < D_UP; ++m) o[m] += r * wr[m];
    }

    float4* op = (float4*)(out + (size_t)i * D_UP);
#pragma unroll
    for (int m4 = 0; m4 < D_UP / 4; ++m4)
        op[m4] = make_float4(o[4 * m4], o[4 * m4 + 1], o[4 * m4 + 2], o[4 * m4 + 3]);
}

extern "C" void kernel_launch(void* const* d_in, const int* in_sizes, int n_in,
                              void* d_out, int out_size, void* d_ws, size_t ws_size,
                              hipStream_t stream) {
    const float* x    = (const float*)d_in[0];
    // d_in[1] = degrees — unused by the reference computation
    const float* ef   = (const float*)d_in[2];
    const float* W1m  = (const float*)d_in[3];
    const float* b1m  = (const float*)d_in[4];
    const float* W2m  = (const float*)d_in[5];
    const float* b2m  = (const float*)d_in[6];
    const float* W1u  = (const float*)d_in[7];
    const float* b1u  = (const float*)d_in[8];
    const float* W2u  = (const float*)d_in[9];
    const float* b2u  = (const float*)d_in[10];
    const int*   ei   = (const int*)d_in[11];

    const int n_nodes = in_sizes[0] / D_IN;      // 50000
    const int n_edges = in_sizes[11] / 2;        // 1600000

    float* out = (float*)d_out;

    // Workspace layout (all 16B-aligned given n_nodes*dims are multiples of 4):
    //   agg  : n_nodes * D_MSG  f  (6.4 MB)
    //   P1   : n_nodes * D_H    f  (12.8 MB)
    //   P2   : n_nodes * D_H    f  (12.8 MB)
    //   deg  : n_nodes          i  (0.2 MB)
    //   offs : n_nodes          i
    //   cursor: n_nodes         i
    //   eidx : n_edges          i  (6.4 MB)
    float* agg    = (float*)d_ws;
    float* P1     = agg + (size_t)n_nodes * D_MSG;
    float* P2     = P1  + (size_t)n_nodes * D_H;
    int*   deg    = (int*)(P2 + (size_t)n_nodes * D_H);
    int*   offs   = deg    + n_nodes;
    int*   cursor = offs   + n_nodes;
    int*   eidx   = cursor + n_nodes;

    hipMemsetAsync(deg, 0, (size_t)n_nodes * sizeof(int), stream);

    {
        int blk = 256;
        int grid = (n_nodes + blk - 1) / blk;
        node_pre_kernel<<<grid, blk, 0, stream>>>(x, W1m, b1m, P1, P2, n_nodes);
    }
    {
        int blk = 256;
        int grid = (n_edges + blk - 1) / blk;
        hist_kernel<<<grid, blk, 0, stream>>>(ei, deg, n_edges);
    }
    scan_kernel<<<1, 1024, 0, stream>>>(deg, offs, cursor, n_nodes);
    {
        int blk = 256;
        int grid = (n_edges + blk - 1) / blk;
        scatter_kernel<<<grid, blk, 0, stream>>>(ei, cursor, eidx, n_edges);
    }
    {
        int blk = 256;
        long total = (long)n_nodes * 8;
        int grid = (int)((total + blk - 1) / blk);
        gather_kernel<<<grid, blk, 0, stream>>>(ef, W1m, W2m, ei, P1, P2,
                                                deg, offs, eidx, agg,
                                                n_nodes, n_edges);
    }
    {
        int blk = 256;
        int grid = (n_nodes + blk - 1) / blk;
        node_upd_kernel<<<grid, blk, 0, stream>>>(x, agg, deg, b2m,
                                                  W1u, b1u, W2u, b2u, out, n_nodes);
    }
}

// Round 3
// 776.956 us; speedup vs baseline: 3.8227x; 1.5473x over previous
//
#include <hip/hip_runtime.h>
#include <hip/hip_bf16.h>

#define D_IN  32
#define D_EF  16
#define D_H   64
#define D_MSG 32
#define D_UP  32

// ---------------------------------------------------------------------------
// Kernel 1: per-node precompute of the message-MLP first-layer partials.
//   P1[n] = x[n] @ W1m[0:32, :]  + b1m   (consumed by owning node n == dst)
//   P2[n] = x[n] @ W1m[32:64, :]         (consumed indexed by src)
// ---------------------------------------------------------------------------
__global__ __launch_bounds__(256) void node_pre_kernel(
    const float* __restrict__ x,
    const float* __restrict__ W1m,
    const float* __restrict__ b1m,
    float* __restrict__ P1,
    float* __restrict__ P2,
    int n_nodes)
{
    int i = blockIdx.x * blockDim.x + threadIdx.x;
    if (i >= n_nodes) return;

    float xi[D_IN];
    const float4* xp = (const float4*)(x + (size_t)i * D_IN);
#pragma unroll
    for (int k4 = 0; k4 < D_IN / 4; ++k4) {
        float4 v = xp[k4];
        xi[4 * k4 + 0] = v.x; xi[4 * k4 + 1] = v.y;
        xi[4 * k4 + 2] = v.z; xi[4 * k4 + 3] = v.w;
    }

    {
        float acc[D_H];
#pragma unroll
        for (int j = 0; j < D_H; ++j) acc[j] = b1m[j];
        for (int k = 0; k < D_IN; ++k) {
            float xv = xi[k];
            const float* wr = W1m + (size_t)k * D_H;
#pragma unroll
            for (int j = 0; j < D_H; ++j) acc[j] += xv * wr[j];
        }
        float4* o = (float4*)(P1 + (size_t)i * D_H);
#pragma unroll
        for (int j4 = 0; j4 < D_H / 4; ++j4)
            o[j4] = make_float4(acc[4 * j4], acc[4 * j4 + 1], acc[4 * j4 + 2], acc[4 * j4 + 3]);
    }
    {
        float acc[D_H];
#pragma unroll
        for (int j = 0; j < D_H; ++j) acc[j] = 0.0f;
        for (int k = 0; k < D_IN; ++k) {
            float xv = xi[k];
            const float* wr = W1m + (size_t)(k + D_IN) * D_H;
#pragma unroll
            for (int j = 0; j < D_H; ++j) acc[j] += xv * wr[j];
        }
        float4* o = (float4*)(P2 + (size_t)i * D_H);
#pragma unroll
        for (int j4 = 0; j4 < D_H / 4; ++j4)
            o[j4] = make_float4(acc[4 * j4], acc[4 * j4 + 1], acc[4 * j4 + 2], acc[4 * j4 + 3]);
    }
}

// ---------------------------------------------------------------------------
// CSR build: histogram -> scan -> scatter
// ---------------------------------------------------------------------------
__global__ __launch_bounds__(256) void hist_kernel(
    const int* __restrict__ ei, int* __restrict__ deg, int n_edges)
{
    int e = blockIdx.x * blockDim.x + threadIdx.x;
    if (e < n_edges) atomicAdd(&deg[ei[n_edges + e]], 1);
}

__global__ __launch_bounds__(1024) void scan_kernel(
    const int* __restrict__ deg,
    int* __restrict__ offs,
    int* __restrict__ cursor,
    int n_nodes)
{
    __shared__ int sdata[1024];
    int t = threadIdx.x;
    int C = (n_nodes + 1023) / 1024;
    int base = t * C;

    int local = 0;
    for (int i = 0; i < C; ++i) {
        int idx = base + i;
        if (idx < n_nodes) local += deg[idx];
    }
    sdata[t] = local;
    __syncthreads();
    for (int off = 1; off < 1024; off <<= 1) {
        int v = (t >= off) ? sdata[t - off] : 0;
        __syncthreads();
        sdata[t] += v;
        __syncthreads();
    }
    int run = (t > 0) ? sdata[t - 1] : 0;
    for (int i = 0; i < C; ++i) {
        int idx = base + i;
        if (idx < n_nodes) {
            offs[idx]   = run;
            cursor[idx] = run;
            run += deg[idx];
        }
    }
}

__global__ __launch_bounds__(256) void scatter_kernel(
    const int* __restrict__ ei,
    int* __restrict__ cursor,
    int* __restrict__ eidx,
    int n_edges)
{
    int e = blockIdx.x * blockDim.x + threadIdx.x;
    if (e < n_edges) {
        int d = ei[n_edges + e];
        int pos = atomicAdd(&cursor[d], 1);
        eidx[pos] = e;
    }
}

// ---------------------------------------------------------------------------
// Gather-aggregate, chunked-h (spill-free). 8 threads per node.
//   For each edge in node n's bucket:
//     for chunk j of 8 h-components:
//       h8 = P1[n][8j..] + P2[src][8j..] + ef[e] @ W1E[:, 8j..8j+8)
//       msg += relu(h8) @ W2m[8j..8j+8, :]
//   Lane-group (8) reduce, lane 0 writes agg[n].
//   (per-edge b2m bias folded into node_upd as deg[n]*b2m)
// Live state: msg[32] + efr[16] + h[8] -> no scratch spill (round-2 version
// kept h[64]+msg[32] live => 561 MB scratch traffic, VALUBusy 14.5%).
// ---------------------------------------------------------------------------
__global__ __launch_bounds__(256) void gather_kernel(
    const float* __restrict__ ef,
    const float* __restrict__ W1m,
    const float* __restrict__ W2m,
    const int*   __restrict__ ei,
    const float* __restrict__ P1,
    const float* __restrict__ P2,
    const int*   __restrict__ deg,
    const int*   __restrict__ offs,
    const int*   __restrict__ eidx,
    float* __restrict__ agg,
    int n_nodes, int n_edges)
{
    int tid = blockIdx.x * blockDim.x + threadIdx.x;
    int n = tid >> 3;
    int t = tid & 7;
    if (n >= n_nodes) return;

    int start = offs[n];
    int end   = start + deg[n];
    const float* W1E = W1m + (size_t)(2 * D_IN) * D_H;
    const float* P1n = P1 + (size_t)n * D_H;

    float msg[D_MSG];
#pragma unroll
    for (int m = 0; m < D_MSG; ++m) msg[m] = 0.0f;

    for (int i = start + t; i < end; i += 8) {
        int e = eidx[i];
        int s = ei[e];

        float efr[D_EF];
        const float4* efp = (const float4*)(ef + (size_t)e * D_EF);
#pragma unroll
        for (int k4 = 0; k4 < D_EF / 4; ++k4) {
            float4 v = efp[k4];
            efr[4 * k4 + 0] = v.x; efr[4 * k4 + 1] = v.y;
            efr[4 * k4 + 2] = v.z; efr[4 * k4 + 3] = v.w;
        }

        const float* P2s = P2 + (size_t)s * D_H;

#pragma unroll 1   // keep rolled: bounds code size; weight indices stay uniform (s_load)
        for (int j = 0; j < D_H / 8; ++j) {
            float h[8];
            const float4* p1 = (const float4*)(P1n + 8 * j);
            const float4* p2 = (const float4*)(P2s + 8 * j);
            float4 a0 = p1[0], a1 = p1[1];
            float4 b0 = p2[0], b1 = p2[1];
            h[0] = a0.x + b0.x; h[1] = a0.y + b0.y;
            h[2] = a0.z + b0.z; h[3] = a0.w + b0.w;
            h[4] = a1.x + b1.x; h[5] = a1.y + b1.y;
            h[6] = a1.z + b1.z; h[7] = a1.w + b1.w;

#pragma unroll
            for (int k = 0; k < D_EF; ++k) {
                float ev = efr[k];
                const float* wr = W1E + (size_t)k * D_H + 8 * j;
#pragma unroll
                for (int c = 0; c < 8; ++c) h[c] += ev * wr[c];
            }

#pragma unroll
            for (int c = 0; c < 8; ++c) {
                float r = h[c] > 0.0f ? h[c] : 0.0f;
                const float* wr = W2m + (size_t)(8 * j + c) * D_MSG;
#pragma unroll
                for (int m = 0; m < D_MSG; ++m) msg[m] += r * wr[m];
            }
        }
    }

    // reduce partial msg across the node's 8 lanes
#pragma unroll
    for (int m = 0; m < D_MSG; ++m) {
        float v = msg[m];
        v += __shfl_xor(v, 1, 8);
        v += __shfl_xor(v, 2, 8);
        v += __shfl_xor(v, 4, 8);
        msg[m] = v;
    }

    if (t == 0) {
        float4* ap = (float4*)(agg + (size_t)n * D_MSG);
#pragma unroll
        for (int m4 = 0; m4 < D_MSG / 4; ++m4)
            ap[m4] = make_float4(msg[4 * m4], msg[4 * m4 + 1],
                                 msg[4 * m4 + 2], msg[4 * m4 + 3]);
    }
}

// ---------------------------------------------------------------------------
// Per-node update MLP (adds deg[n]*b2m to agg on the fly).
//   out = relu([x, agg + deg*b2m] @ W1u + b1u) @ W2u + b2u
// ---------------------------------------------------------------------------
__global__ __launch_bounds__(256) void node_upd_kernel(
    const float* __restrict__ x,
    const float* __restrict__ agg,
    const int*   __restrict__ deg,
    const float* __restrict__ b2m,
    const float* __restrict__ W1u,
    const float* __restrict__ b1u,
    const float* __restrict__ W2u,
    const float* __restrict__ b2u,
    float* __restrict__ out,
    int n_nodes)
{
    int i = blockIdx.x * blockDim.x + threadIdx.x;
    if (i >= n_nodes) return;

    float in[D_IN + D_MSG];
    const float4* xp = (const float4*)(x + (size_t)i * D_IN);
#pragma unroll
    for (int k4 = 0; k4 < D_IN / 4; ++k4) {
        float4 v = xp[k4];
        in[4 * k4 + 0] = v.x; in[4 * k4 + 1] = v.y;
        in[4 * k4 + 2] = v.z; in[4 * k4 + 3] = v.w;
    }
    float dc = (float)deg[i];
    const float4* ap = (const float4*)(agg + (size_t)i * D_MSG);
#pragma unroll
    for (int k4 = 0; k4 < D_MSG / 4; ++k4) {
        float4 v = ap[k4];
        in[D_IN + 4 * k4 + 0] = v.x + dc * b2m[4 * k4 + 0];
        in[D_IN + 4 * k4 + 1] = v.y + dc * b2m[4 * k4 + 1];
        in[D_IN + 4 * k4 + 2] = v.z + dc * b2m[4 * k4 + 2];
        in[D_IN + 4 * k4 + 3] = v.w + dc * b2m[4 * k4 + 3];
    }

    float h[D_H];
#pragma unroll
    for (int j = 0; j < D_H; ++j) h[j] = b1u[j];
    for (int k = 0; k < D_IN + D_MSG; ++k) {
        float v = in[k];
        const float* wr = W1u + (size_t)k * D_H;
#pragma unroll
        for (int j = 0; j < D_H; ++j) h[j] += v * wr[j];
    }

    float o[D_UP];
#pragma unroll
    for (int m = 0; m < D_UP; ++m) o[m] = b2u[m];
    for (int j = 0; j < D_H; ++j) {
        float r = h[j] > 0.0f ? h[j] : 0.0f;
        const float* wr = W2u + (size_t)j * D_UP;
#pragma unroll
        for (int m = 0; m < D_UP; ++m) o[m] += r * wr[m];
    }

    float4* op = (float4*)(out + (size_t)i * D_UP);
#pragma unroll
    for (int m4 = 0; m4 < D_UP / 4; ++m4)
        op[m4] = make_float4(o[4 * m4], o[4 * m4 + 1], o[4 * m4 + 2], o[4 * m4 + 3]);
}

extern "C" void kernel_launch(void* const* d_in, const int* in_sizes, int n_in,
                              void* d_out, int out_size, void* d_ws, size_t ws_size,
                              hipStream_t stream) {
    const float* x    = (const float*)d_in[0];
    // d_in[1] = degrees — unused by the reference computation
    const float* ef   = (const float*)d_in[2];
    const float* W1m  = (const float*)d_in[3];
    const float* b1m  = (const float*)d_in[4];
    const float* W2m  = (const float*)d_in[5];
    const float* b2m  = (const float*)d_in[6];
    const float* W1u  = (const float*)d_in[7];
    const float* b1u  = (const float*)d_in[8];
    const float* W2u  = (const float*)d_in[9];
    const float* b2u  = (const float*)d_in[10];
    const int*   ei   = (const int*)d_in[11];

    const int n_nodes = in_sizes[0] / D_IN;      // 50000
    const int n_edges = in_sizes[11] / 2;        // 1600000

    float* out = (float*)d_out;

    // Workspace layout:
    //   agg  : n_nodes * D_MSG  f  (6.4 MB)
    //   P1   : n_nodes * D_H    f  (12.8 MB)
    //   P2   : n_nodes * D_H    f  (12.8 MB)
    //   deg  : n_nodes          i
    //   offs : n_nodes          i
    //   cursor: n_nodes         i
    //   eidx : n_edges          i  (6.4 MB)
    float* agg    = (float*)d_ws;
    float* P1     = agg + (size_t)n_nodes * D_MSG;
    float* P2     = P1  + (size_t)n_nodes * D_H;
    int*   deg    = (int*)(P2 + (size_t)n_nodes * D_H);
    int*   offs   = deg    + n_nodes;
    int*   cursor = offs   + n_nodes;
    int*   eidx   = cursor + n_nodes;

    hipMemsetAsync(deg, 0, (size_t)n_nodes * sizeof(int), stream);

    {
        int blk = 256;
        int grid = (n_nodes + blk - 1) / blk;
        node_pre_kernel<<<grid, blk, 0, stream>>>(x, W1m, b1m, P1, P2, n_nodes);
    }
    {
        int blk = 256;
        int grid = (n_edges + blk - 1) / blk;
        hist_kernel<<<grid, blk, 0, stream>>>(ei, deg, n_edges);
    }
    scan_kernel<<<1, 1024, 0, stream>>>(deg, offs, cursor, n_nodes);
    {
        int blk = 256;
        int grid = (n_edges + blk - 1) / blk;
        scatter_kernel<<<grid, blk, 0, stream>>>(ei, cursor, eidx, n_edges);
    }
    {
        int blk = 256;
        long total = (long)n_nodes * 8;
        int grid = (int)((total + blk - 1) / blk);
        gather_kernel<<<grid, blk, 0, stream>>>(ef, W1m, W2m, ei, P1, P2,
                                                deg, offs, eidx, agg,
                                                n_nodes, n_edges);
    }
    {
        int blk = 256;
        int grid = (n_nodes + blk - 1) / blk;
        node_upd_kernel<<<grid, blk, 0, stream>>>(x, agg, deg, b2m,
                                                  W1u, b1u, W2u, b2u, out, n_nodes);
    }
}

// Round 4
// 651.487 us; speedup vs baseline: 4.5589x; 1.1926x over previous
//
#include <hip/hip_runtime.h>
#include <hip/hip_bf16.h>

#define D_IN  32
#define D_EF  16
#define D_H   64
#define D_MSG 32
#define D_UP  32

// ---------------------------------------------------------------------------
// Kernel 1: per-node precompute of the message-MLP first-layer partials.
//   P1[n] = x[n] @ W1m[0:32, :]  + b1m   (consumed by owning node n == dst)
//   P2[n] = x[n] @ W1m[32:64, :]         (consumed indexed by src)
// ---------------------------------------------------------------------------
__global__ __launch_bounds__(256) void node_pre_kernel(
    const float* __restrict__ x,
    const float* __restrict__ W1m,
    const float* __restrict__ b1m,
    float* __restrict__ P1,
    float* __restrict__ P2,
    int n_nodes)
{
    int i = blockIdx.x * blockDim.x + threadIdx.x;
    if (i >= n_nodes) return;

    float xi[D_IN];
    const float4* xp = (const float4*)(x + (size_t)i * D_IN);
#pragma unroll
    for (int k4 = 0; k4 < D_IN / 4; ++k4) {
        float4 v = xp[k4];
        xi[4 * k4 + 0] = v.x; xi[4 * k4 + 1] = v.y;
        xi[4 * k4 + 2] = v.z; xi[4 * k4 + 3] = v.w;
    }

    {
        float acc[D_H];
#pragma unroll
        for (int j = 0; j < D_H; ++j) acc[j] = b1m[j];
        for (int k = 0; k < D_IN; ++k) {
            float xv = xi[k];
            const float* wr = W1m + (size_t)k * D_H;
#pragma unroll
            for (int j = 0; j < D_H; ++j) acc[j] += xv * wr[j];
        }
        float4* o = (float4*)(P1 + (size_t)i * D_H);
#pragma unroll
        for (int j4 = 0; j4 < D_H / 4; ++j4)
            o[j4] = make_float4(acc[4 * j4], acc[4 * j4 + 1], acc[4 * j4 + 2], acc[4 * j4 + 3]);
    }
    {
        float acc[D_H];
#pragma unroll
        for (int j = 0; j < D_H; ++j) acc[j] = 0.0f;
        for (int k = 0; k < D_IN; ++k) {
            float xv = xi[k];
            const float* wr = W1m + (size_t)(k + D_IN) * D_H;
#pragma unroll
            for (int j = 0; j < D_H; ++j) acc[j] += xv * wr[j];
        }
        float4* o = (float4*)(P2 + (size_t)i * D_H);
#pragma unroll
        for (int j4 = 0; j4 < D_H / 4; ++j4)
            o[j4] = make_float4(acc[4 * j4], acc[4 * j4 + 1], acc[4 * j4 + 2], acc[4 * j4 + 3]);
    }
}

// ---------------------------------------------------------------------------
// CSR build: histogram -> 3-phase multi-block scan -> scatter
// (round-3's single-block scan ran on 1 CU; suspected ~100 µs)
// ---------------------------------------------------------------------------
__global__ __launch_bounds__(256) void hist_kernel(
    const int* __restrict__ ei, int* __restrict__ deg, int n_edges)
{
    int e = blockIdx.x * blockDim.x + threadIdx.x;
    if (e < n_edges) atomicAdd(&deg[ei[n_edges + e]], 1);
}

// phase A: per-block sums of deg
__global__ __launch_bounds__(256) void scan_partials_kernel(
    const int* __restrict__ deg, int* __restrict__ bsum, int n_nodes)
{
    int idx = blockIdx.x * 256 + threadIdx.x;
    int v = (idx < n_nodes) ? deg[idx] : 0;
#pragma unroll
    for (int o = 1; o < 64; o <<= 1) v += __shfl_xor(v, o, 64);
    __shared__ int ws[4];
    int lane = threadIdx.x & 63, w = threadIdx.x >> 6;
    if (lane == 0) ws[w] = v;
    __syncthreads();
    if (threadIdx.x == 0) bsum[blockIdx.x] = ws[0] + ws[1] + ws[2] + ws[3];
}

// phase B: exclusive scan of the (<=256) block partials, one block
__global__ __launch_bounds__(256) void scan_blockoffs_kernel(
    const int* __restrict__ bsum, int* __restrict__ boffs, int nb)
{
    __shared__ int sdata[256];
    int t = threadIdx.x;
    sdata[t] = (t < nb) ? bsum[t] : 0;
    __syncthreads();
    for (int off = 1; off < 256; off <<= 1) {
        int u = (t >= off) ? sdata[t - off] : 0;
        __syncthreads();
        sdata[t] += u;
        __syncthreads();
    }
    if (t < nb) boffs[t] = (t > 0) ? sdata[t - 1] : 0;
}

// phase C: per-block local exclusive scan + block offset -> offs/cursor
__global__ __launch_bounds__(256) void scan_final_kernel(
    const int* __restrict__ deg, const int* __restrict__ boffs,
    int* __restrict__ offs, int* __restrict__ cursor, int n_nodes)
{
    __shared__ int sdata[256];
    int t = threadIdx.x;
    int idx = blockIdx.x * 256 + t;
    sdata[t] = (idx < n_nodes) ? deg[idx] : 0;
    __syncthreads();
    for (int off = 1; off < 256; off <<= 1) {
        int u = (t >= off) ? sdata[t - off] : 0;
        __syncthreads();
        sdata[t] += u;
        __syncthreads();
    }
    int excl = boffs[blockIdx.x] + ((t > 0) ? sdata[t - 1] : 0);
    if (idx < n_nodes) { offs[idx] = excl; cursor[idx] = excl; }
}

__global__ __launch_bounds__(256) void scatter_kernel(
    const int* __restrict__ ei,
    int* __restrict__ cursor,
    int* __restrict__ eidx,
    int n_edges)
{
    int e = blockIdx.x * blockDim.x + threadIdx.x;
    if (e < n_edges) {
        int d = ei[n_edges + e];
        int pos = atomicAdd(&cursor[d], 1);
        eidx[pos] = e;
    }
}

// ---------------------------------------------------------------------------
// Gather-aggregate, chunked-h, software-pipelined. 16 threads per node.
//   For each edge in node n's bucket:
//     for chunk j of 8 h-components:
//       h8 = P1[n][8j..] + P2[src][8j..] + ef[e] @ W1E[:, 8j..8j+8)
//       msg += relu(h8) @ W2m[8j..8j+8, :]
//   Pipelining: next edge's eidx/ei/ef row is loaded before the current
//   edge's compute; next chunk's P2 pair is loaded before the current
//   chunk's FMAs. Clamped indices keep the prefetch loads unconditional.
//   (per-edge b2m bias folded into node_upd as deg[n]*b2m)
// ---------------------------------------------------------------------------
__global__ __launch_bounds__(256) void gather_kernel(
    const float* __restrict__ ef,
    const float* __restrict__ W1m,
    const float* __restrict__ W2m,
    const int*   __restrict__ ei,
    const float* __restrict__ P1,
    const float* __restrict__ P2,
    const int*   __restrict__ deg,
    const int*   __restrict__ offs,
    const int*   __restrict__ eidx,
    float* __restrict__ agg,
    int n_nodes, int n_edges)
{
    int tid = blockIdx.x * blockDim.x + threadIdx.x;
    int n = tid >> 4;
    int t = tid & 15;
    if (n >= n_nodes) return;

    int start = offs[n];
    int end   = start + deg[n];
    const float* W1E = W1m + (size_t)(2 * D_IN) * D_H;
    const float* P1n = P1 + (size_t)n * D_H;

    float msg[D_MSG];
#pragma unroll
    for (int m = 0; m < D_MSG; ++m) msg[m] = 0.0f;

    int i = start + t;
    int s = 0;
    float4 ef0, ef1, ef2, ef3;
    if (i < end) {
        int e = eidx[i];
        s = ei[e];
        const float4* efp = (const float4*)(ef + (size_t)e * D_EF);
        ef0 = efp[0]; ef1 = efp[1]; ef2 = efp[2]; ef3 = efp[3];
    }

    while (i < end) {
        // ---- prefetch next edge (clamped -> unconditional, always valid) ----
        int inext = i + 16;
        int ip = (inext < end) ? inext : i;
        int e2 = eidx[ip];
        int s2 = ei[e2];
        const float4* efp2 = (const float4*)(ef + (size_t)e2 * D_EF);
        float4 nf0 = efp2[0], nf1 = efp2[1], nf2 = efp2[2], nf3 = efp2[3];

        float efr[D_EF] = {ef0.x, ef0.y, ef0.z, ef0.w,
                           ef1.x, ef1.y, ef1.z, ef1.w,
                           ef2.x, ef2.y, ef2.z, ef2.w,
                           ef3.x, ef3.y, ef3.z, ef3.w};

        const float4* p1 = (const float4*)P1n;
        const float4* p2 = (const float4*)(P2 + (size_t)s * D_H);
        float4 b0 = p2[0], b1 = p2[1];

#pragma unroll 1   // rolled: bounds code size; weight accesses stay uniform (s_load)
        for (int j = 0; j < D_H / 8; ++j) {
            // prefetch next chunk's P2 pair (clamp to 0 on last chunk)
            int jn = (j < D_H / 8 - 1) ? (2 * j + 2) : 0;
            float4 c0 = p2[jn], c1 = p2[jn + 1];

            float4 a0 = p1[2 * j], a1 = p1[2 * j + 1];
            float h[8];
            h[0] = a0.x + b0.x; h[1] = a0.y + b0.y;
            h[2] = a0.z + b0.z; h[3] = a0.w + b0.w;
            h[4] = a1.x + b1.x; h[5] = a1.y + b1.y;
            h[6] = a1.z + b1.z; h[7] = a1.w + b1.w;

#pragma unroll
            for (int k = 0; k < D_EF; ++k) {
                float ev = efr[k];
                const float* wr = W1E + (size_t)k * D_H + 8 * j;
#pragma unroll
                for (int c = 0; c < 8; ++c) h[c] += ev * wr[c];
            }

#pragma unroll
            for (int c = 0; c < 8; ++c) {
                float r = h[c] > 0.0f ? h[c] : 0.0f;
                const float* wr = W2m + (size_t)(8 * j + c) * D_MSG;
#pragma unroll
                for (int m = 0; m < D_MSG; ++m) msg[m] += r * wr[m];
            }
            b0 = c0; b1 = c1;
        }

        i = inext; s = s2;
        ef0 = nf0; ef1 = nf1; ef2 = nf2; ef3 = nf3;
    }

    // reduce partial msg across the node's 16 lanes
#pragma unroll
    for (int m = 0; m < D_MSG; ++m) {
        float v = msg[m];
        v += __shfl_xor(v, 1, 16);
        v += __shfl_xor(v, 2, 16);
        v += __shfl_xor(v, 4, 16);
        v += __shfl_xor(v, 8, 16);
        msg[m] = v;
    }

    if (t == 0) {
        float4* ap = (float4*)(agg + (size_t)n * D_MSG);
#pragma unroll
        for (int m4 = 0; m4 < D_MSG / 4; ++m4)
            ap[m4] = make_float4(msg[4 * m4], msg[4 * m4 + 1],
                                 msg[4 * m4 + 2], msg[4 * m4 + 3]);
    }
}

// ---------------------------------------------------------------------------
// Per-node update MLP (adds deg[n]*b2m to agg on the fly).
//   out = relu([x, agg + deg*b2m] @ W1u + b1u) @ W2u + b2u
// ---------------------------------------------------------------------------
__global__ __launch_bounds__(256) void node_upd_kernel(
    const float* __restrict__ x,
    const float* __restrict__ agg,
    const int*   __restrict__ deg,
    const float* __restrict__ b2m,
    const float* __restrict__ W1u,
    const float* __restrict__ b1u,
    const float* __restrict__ W2u,
    const float* __restrict__ b2u,
    float* __restrict__ out,
    int n_nodes)
{
    int i = blockIdx.x * blockDim.x + threadIdx.x;
    if (i >= n_nodes) return;

    float in[D_IN + D_MSG];
    const float4* xp = (const float4*)(x + (size_t)i * D_IN);
#pragma unroll
    for (int k4 = 0; k4 < D_IN / 4; ++k4) {
        float4 v = xp[k4];
        in[4 * k4 + 0] = v.x; in[4 * k4 + 1] = v.y;
        in[4 * k4 + 2] = v.z; in[4 * k4 + 3] = v.w;
    }
    float dc = (float)deg[i];
    const float4* ap = (const float4*)(agg + (size_t)i * D_MSG);
#pragma unroll
    for (int k4 = 0; k4 < D_MSG / 4; ++k4) {
        float4 v = ap[k4];
        in[D_IN + 4 * k4 + 0] = v.x + dc * b2m[4 * k4 + 0];
        in[D_IN + 4 * k4 + 1] = v.y + dc * b2m[4 * k4 + 1];
        in[D_IN + 4 * k4 + 2] = v.z + dc * b2m[4 * k4 + 2];
        in[D_IN + 4 * k4 + 3] = v.w + dc * b2m[4 * k4 + 3];
    }

    float h[D_H];
#pragma unroll
    for (int j = 0; j < D_H; ++j) h[j] = b1u[j];
    for (int k = 0; k < D_IN + D_MSG; ++k) {
        float v = in[k];
        const float* wr = W1u + (size_t)k * D_H;
#pragma unroll
        for (int j = 0; j < D_H; ++j) h[j] += v * wr[j];
    }

    float o[D_UP];
#pragma unroll
    for (int m = 0; m < D_UP; ++m) o[m] = b2u[m];
    for (int j = 0; j < D_H; ++j) {
        float r = h[j] > 0.0f ? h[j] : 0.0f;
        const float* wr = W2u + (size_t)j * D_UP;
#pragma unroll
        for (int m = 0; m < D_UP; ++m) o[m] += r * wr[m];
    }

    float4* op = (float4*)(out + (size_t)i * D_UP);
#pragma unroll
    for (int m4 = 0; m4 < D_UP / 4; ++m4)
        op[m4] = make_float4(o[4 * m4], o[4 * m4 + 1], o[4 * m4 + 2], o[4 * m4 + 3]);
}

extern "C" void kernel_launch(void* const* d_in, const int* in_sizes, int n_in,
                              void* d_out, int out_size, void* d_ws, size_t ws_size,
                              hipStream_t stream) {
    const float* x    = (const float*)d_in[0];
    // d_in[1] = degrees — unused by the reference computation
    const float* ef   = (const float*)d_in[2];
    const float* W1m  = (const float*)d_in[3];
    const float* b1m  = (const float*)d_in[4];
    const float* W2m  = (const float*)d_in[5];
    const float* b2m  = (const float*)d_in[6];
    const float* W1u  = (const float*)d_in[7];
    const float* b1u  = (const float*)d_in[8];
    const float* W2u  = (const float*)d_in[9];
    const float* b2u  = (const float*)d_in[10];
    const int*   ei   = (const int*)d_in[11];

    const int n_nodes = in_sizes[0] / D_IN;      // 50000
    const int n_edges = in_sizes[11] / 2;        // 1600000

    float* out = (float*)d_out;

    const int NB = (n_nodes + 255) / 256;        // 196 scan blocks (<=256 req'd)

    // Workspace layout:
    //   agg  : n_nodes * D_MSG  f  (6.4 MB)
    //   P1   : n_nodes * D_H    f  (12.8 MB)
    //   P2   : n_nodes * D_H    f  (12.8 MB)
    //   deg  : n_nodes          i
    //   offs : n_nodes          i
    //   cursor: n_nodes         i
    //   eidx : n_edges          i  (6.4 MB)
    //   bsum : NB               i
    //   boffs: NB               i
    float* agg    = (float*)d_ws;
    float* P1     = agg + (size_t)n_nodes * D_MSG;
    float* P2     = P1  + (size_t)n_nodes * D_H;
    int*   deg    = (int*)(P2 + (size_t)n_nodes * D_H);
    int*   offs   = deg    + n_nodes;
    int*   cursor = offs   + n_nodes;
    int*   eidx   = cursor + n_nodes;
    int*   bsum   = eidx   + n_edges;
    int*   boffs  = bsum   + NB;

    hipMemsetAsync(deg, 0, (size_t)n_nodes * sizeof(int), stream);

    {
        int blk = 256;
        int grid = (n_nodes + blk - 1) / blk;
        node_pre_kernel<<<grid, blk, 0, stream>>>(x, W1m, b1m, P1, P2, n_nodes);
    }
    {
        int blk = 256;
        int grid = (n_edges + blk - 1) / blk;
        hist_kernel<<<grid, blk, 0, stream>>>(ei, deg, n_edges);
    }
    scan_partials_kernel<<<NB, 256, 0, stream>>>(deg, bsum, n_nodes);
    scan_blockoffs_kernel<<<1, 256, 0, stream>>>(bsum, boffs, NB);
    scan_final_kernel<<<NB, 256, 0, stream>>>(deg, boffs, offs, cursor, n_nodes);
    {
        int blk = 256;
        int grid = (n_edges + blk - 1) / blk;
        scatter_kernel<<<grid, blk, 0, stream>>>(ei, cursor, eidx, n_edges);
    }
    {
        int blk = 256;
        long total = (long)n_nodes * 16;
        int grid = (int)((total + blk - 1) / blk);
        gather_kernel<<<grid, blk, 0, stream>>>(ef, W1m, W2m, ei, P1, P2,
                                                deg, offs, eidx, agg,
                                                n_nodes, n_edges);
    }
    {
        int blk = 256;
        int grid = (n_nodes + blk - 1) / blk;
        node_upd_kernel<<<grid, blk, 0, stream>>>(x, agg, deg, b2m,
                                                  W1u, b1u, W2u, b2u, out, n_nodes);
    }
}

// Round 5
// 637.788 us; speedup vs baseline: 4.6568x; 1.0215x over previous
//
#include <hip/hip_runtime.h>
#include <hip/hip_bf16.h>

#define D_IN  32
#define D_EF  16
#define D_H   64
#define D_MSG 32
#define D_UP  32

// bf16 helpers: pack two fp32 -> uint32 (RNE), unpack low/high half
__device__ __forceinline__ unsigned bf16pair(float a, float b) {
    unsigned ua = __float_as_uint(a);
    ua = (ua + 0x7fffu + ((ua >> 16) & 1u)) >> 16;
    unsigned ub = __float_as_uint(b);
    ub = (ub + 0x7fffu + ((ub >> 16) & 1u)) >> 16;
    return ua | (ub << 16);
}
__device__ __forceinline__ float bf_lo(unsigned u) { return __uint_as_float(u << 16); }
__device__ __forceinline__ float bf_hi(unsigned u) { return __uint_as_float(u & 0xffff0000u); }

// ---------------------------------------------------------------------------
// Kernel 1: per-node precompute of the message-MLP first-layer partials.
//   P1[n] = x[n] @ W1m[0:32, :]  + b1m   (fp32, consumed by owning node n==dst)
//   P2[n] = x[n] @ W1m[32:64, :]         (bf16, gathered by src -> half traffic)
// ---------------------------------------------------------------------------
__global__ __launch_bounds__(256) void node_pre_kernel(
    const float* __restrict__ x,
    const float* __restrict__ W1m,
    const float* __restrict__ b1m,
    float* __restrict__ P1,
    unsigned short* __restrict__ P2b,
    int n_nodes)
{
    int i = blockIdx.x * blockDim.x + threadIdx.x;
    if (i >= n_nodes) return;

    float xi[D_IN];
    const float4* xp = (const float4*)(x + (size_t)i * D_IN);
#pragma unroll
    for (int k4 = 0; k4 < D_IN / 4; ++k4) {
        float4 v = xp[k4];
        xi[4 * k4 + 0] = v.x; xi[4 * k4 + 1] = v.y;
        xi[4 * k4 + 2] = v.z; xi[4 * k4 + 3] = v.w;
    }

    {
        float acc[D_H];
#pragma unroll
        for (int j = 0; j < D_H; ++j) acc[j] = b1m[j];
        for (int k = 0; k < D_IN; ++k) {
            float xv = xi[k];
            const float* wr = W1m + (size_t)k * D_H;
#pragma unroll
            for (int j = 0; j < D_H; ++j) acc[j] += xv * wr[j];
        }
        float4* o = (float4*)(P1 + (size_t)i * D_H);
#pragma unroll
        for (int j4 = 0; j4 < D_H / 4; ++j4)
            o[j4] = make_float4(acc[4 * j4], acc[4 * j4 + 1], acc[4 * j4 + 2], acc[4 * j4 + 3]);
    }
    {
        float acc[D_H];
#pragma unroll
        for (int j = 0; j < D_H; ++j) acc[j] = 0.0f;
        for (int k = 0; k < D_IN; ++k) {
            float xv = xi[k];
            const float* wr = W1m + (size_t)(k + D_IN) * D_H;
#pragma unroll
            for (int j = 0; j < D_H; ++j) acc[j] += xv * wr[j];
        }
        uint4* o = (uint4*)(P2b + (size_t)i * D_H);
#pragma unroll
        for (int j8 = 0; j8 < D_H / 8; ++j8) {
            uint4 q;
            q.x = bf16pair(acc[8 * j8 + 0], acc[8 * j8 + 1]);
            q.y = bf16pair(acc[8 * j8 + 2], acc[8 * j8 + 3]);
            q.z = bf16pair(acc[8 * j8 + 4], acc[8 * j8 + 5]);
            q.w = bf16pair(acc[8 * j8 + 6], acc[8 * j8 + 7]);
            o[j8] = q;
        }
    }
}

// ---------------------------------------------------------------------------
// CSR build: histogram -> 3-phase multi-block scan -> scatter
// ---------------------------------------------------------------------------
__global__ __launch_bounds__(256) void hist_kernel(
    const int* __restrict__ ei, int* __restrict__ deg, int n_edges)
{
    int e = blockIdx.x * blockDim.x + threadIdx.x;
    if (e < n_edges) atomicAdd(&deg[ei[n_edges + e]], 1);
}

// phase A: per-block sums of deg
__global__ __launch_bounds__(256) void scan_partials_kernel(
    const int* __restrict__ deg, int* __restrict__ bsum, int n_nodes)
{
    int idx = blockIdx.x * 256 + threadIdx.x;
    int v = (idx < n_nodes) ? deg[idx] : 0;
#pragma unroll
    for (int o = 1; o < 64; o <<= 1) v += __shfl_xor(v, o, 64);
    __shared__ int ws[4];
    int lane = threadIdx.x & 63, w = threadIdx.x >> 6;
    if (lane == 0) ws[w] = v;
    __syncthreads();
    if (threadIdx.x == 0) bsum[blockIdx.x] = ws[0] + ws[1] + ws[2] + ws[3];
}

// phase B: exclusive scan of the (<=256) block partials, one block
__global__ __launch_bounds__(256) void scan_blockoffs_kernel(
    const int* __restrict__ bsum, int* __restrict__ boffs, int nb)
{
    __shared__ int sdata[256];
    int t = threadIdx.x;
    sdata[t] = (t < nb) ? bsum[t] : 0;
    __syncthreads();
    for (int off = 1; off < 256; off <<= 1) {
        int u = (t >= off) ? sdata[t - off] : 0;
        __syncthreads();
        sdata[t] += u;
        __syncthreads();
    }
    if (t < nb) boffs[t] = (t > 0) ? sdata[t - 1] : 0;
}

// phase C: per-block local exclusive scan + block offset -> offs/cursor
__global__ __launch_bounds__(256) void scan_final_kernel(
    const int* __restrict__ deg, const int* __restrict__ boffs,
    int* __restrict__ offs, int* __restrict__ cursor, int n_nodes)
{
    __shared__ int sdata[256];
    int t = threadIdx.x;
    int idx = blockIdx.x * 256 + t;
    sdata[t] = (idx < n_nodes) ? deg[idx] : 0;
    __syncthreads();
    for (int off = 1; off < 256; off <<= 1) {
        int u = (t >= off) ? sdata[t - off] : 0;
        __syncthreads();
        sdata[t] += u;
        __syncthreads();
    }
    int excl = boffs[blockIdx.x] + ((t > 0) ? sdata[t - 1] : 0);
    if (idx < n_nodes) { offs[idx] = excl; cursor[idx] = excl; }
}

// scatter: writes packed (edge_id, src) per slot so gather never touches ei.
__global__ __launch_bounds__(256) void scatter_kernel(
    const int* __restrict__ ei,
    int* __restrict__ cursor,
    int2* __restrict__ edges_sorted,
    int n_edges)
{
    int e = blockIdx.x * blockDim.x + threadIdx.x;
    if (e < n_edges) {
        int s = ei[e];
        int d = ei[n_edges + e];
        int pos = atomicAdd(&cursor[d], 1);
        edges_sorted[pos] = make_int2(e, s);
    }
}

// ---------------------------------------------------------------------------
// Gather-aggregate, chunked-h, software-pipelined. 16 threads per node.
//   For each edge in node n's bucket:
//     for chunk j of 8 h-components:
//       h8 = P1[n][8j..] + bf16(P2[src][8j..]) + ef[e] @ W1E[:, 8j..8j+8)
//       msg += relu(h8) @ W2m[8j..8j+8, :]
//   P2 is bf16 (halves the dominant random-gather traffic: 410 -> 205 MB).
//   edges_sorted packs (e, src): no random ei[] line pulls.
//   (per-edge b2m bias folded into node_upd as deg[n]*b2m)
// ---------------------------------------------------------------------------
__global__ __launch_bounds__(256) void gather_kernel(
    const float* __restrict__ ef,
    const float* __restrict__ W1m,
    const float* __restrict__ W2m,
    const float* __restrict__ P1,
    const unsigned short* __restrict__ P2b,
    const int*  __restrict__ deg,
    const int*  __restrict__ offs,
    const int2* __restrict__ edges_sorted,
    float* __restrict__ agg,
    int n_nodes)
{
    int tid = blockIdx.x * blockDim.x + threadIdx.x;
    int n = tid >> 4;
    int t = tid & 15;
    if (n >= n_nodes) return;

    int start = offs[n];
    int end   = start + deg[n];
    const float* W1E = W1m + (size_t)(2 * D_IN) * D_H;
    const float* P1n = P1 + (size_t)n * D_H;

    float msg[D_MSG];
#pragma unroll
    for (int m = 0; m < D_MSG; ++m) msg[m] = 0.0f;

    int i = start + t;
    int s = 0;
    float4 ef0, ef1, ef2, ef3;
    if (i < end) {
        int2 es = edges_sorted[i];
        s = es.y;
        const float4* efp = (const float4*)(ef + (size_t)es.x * D_EF);
        ef0 = efp[0]; ef1 = efp[1]; ef2 = efp[2]; ef3 = efp[3];
    }

    while (i < end) {
        // ---- prefetch next edge (clamped -> unconditional, always valid) ----
        int inext = i + 16;
        int ip = (inext < end) ? inext : i;
        int2 es2 = edges_sorted[ip];
        const float4* efp2 = (const float4*)(ef + (size_t)es2.x * D_EF);
        float4 nf0 = efp2[0], nf1 = efp2[1], nf2 = efp2[2], nf3 = efp2[3];

        float efr[D_EF] = {ef0.x, ef0.y, ef0.z, ef0.w,
                           ef1.x, ef1.y, ef1.z, ef1.w,
                           ef2.x, ef2.y, ef2.z, ef2.w,
                           ef3.x, ef3.y, ef3.z, ef3.w};

        const float4* p1  = (const float4*)P1n;
        const uint4*  p2u = (const uint4*)(P2b + (size_t)s * D_H);
        uint4 b = p2u[0];

#pragma unroll 1   // rolled: bounds code size; weight accesses stay uniform (s_load)
        for (int j = 0; j < D_H / 8; ++j) {
            int jn = (j < D_H / 8 - 1) ? (j + 1) : 0;
            uint4 c = p2u[jn];           // prefetch next chunk's P2 (bf16 x8)

            float4 a0 = p1[2 * j], a1 = p1[2 * j + 1];
            float h[8];
            h[0] = a0.x + bf_lo(b.x); h[1] = a0.y + bf_hi(b.x);
            h[2] = a0.z + bf_lo(b.y); h[3] = a0.w + bf_hi(b.y);
            h[4] = a1.x + bf_lo(b.z); h[5] = a1.y + bf_hi(b.z);
            h[6] = a1.z + bf_lo(b.w); h[7] = a1.w + bf_hi(b.w);

#pragma unroll
            for (int k = 0; k < D_EF; ++k) {
                float ev = efr[k];
                const float* wr = W1E + (size_t)k * D_H + 8 * j;
#pragma unroll
                for (int c8 = 0; c8 < 8; ++c8) h[c8] += ev * wr[c8];
            }

#pragma unroll
            for (int c8 = 0; c8 < 8; ++c8) {
                float r = h[c8] > 0.0f ? h[c8] : 0.0f;
                const float* wr = W2m + (size_t)(8 * j + c8) * D_MSG;
#pragma unroll
                for (int m = 0; m < D_MSG; ++m) msg[m] += r * wr[m];
            }
            b = c;
        }

        i = inext; s = es2.y;
        ef0 = nf0; ef1 = nf1; ef2 = nf2; ef3 = nf3;
    }

    // reduce partial msg across the node's 16 lanes
#pragma unroll
    for (int m = 0; m < D_MSG; ++m) {
        float v = msg[m];
        v += __shfl_xor(v, 1, 16);
        v += __shfl_xor(v, 2, 16);
        v += __shfl_xor(v, 4, 16);
        v += __shfl_xor(v, 8, 16);
        msg[m] = v;
    }

    if (t == 0) {
        float4* ap = (float4*)(agg + (size_t)n * D_MSG);
#pragma unroll
        for (int m4 = 0; m4 < D_MSG / 4; ++m4)
            ap[m4] = make_float4(msg[4 * m4], msg[4 * m4 + 1],
                                 msg[4 * m4 + 2], msg[4 * m4 + 3]);
    }
}

// ---------------------------------------------------------------------------
// Per-node update MLP (adds deg[n]*b2m to agg on the fly).
//   out = relu([x, agg + deg*b2m] @ W1u + b1u) @ W2u + b2u
// ---------------------------------------------------------------------------
__global__ __launch_bounds__(256) void node_upd_kernel(
    const float* __restrict__ x,
    const float* __restrict__ agg,
    const int*   __restrict__ deg,
    const float* __restrict__ b2m,
    const float* __restrict__ W1u,
    const float* __restrict__ b1u,
    const float* __restrict__ W2u,
    const float* __restrict__ b2u,
    float* __restrict__ out,
    int n_nodes)
{
    int i = blockIdx.x * blockDim.x + threadIdx.x;
    if (i >= n_nodes) return;

    float in[D_IN + D_MSG];
    const float4* xp = (const float4*)(x + (size_t)i * D_IN);
#pragma unroll
    for (int k4 = 0; k4 < D_IN / 4; ++k4) {
        float4 v = xp[k4];
        in[4 * k4 + 0] = v.x; in[4 * k4 + 1] = v.y;
        in[4 * k4 + 2] = v.z; in[4 * k4 + 3] = v.w;
    }
    float dc = (float)deg[i];
    const float4* ap = (const float4*)(agg + (size_t)i * D_MSG);
#pragma unroll
    for (int k4 = 0; k4 < D_MSG / 4; ++k4) {
        float4 v = ap[k4];
        in[D_IN + 4 * k4 + 0] = v.x + dc * b2m[4 * k4 + 0];
        in[D_IN + 4 * k4 + 1] = v.y + dc * b2m[4 * k4 + 1];
        in[D_IN + 4 * k4 + 2] = v.z + dc * b2m[4 * k4 + 2];
        in[D_IN + 4 * k4 + 3] = v.w + dc * b2m[4 * k4 + 3];
    }

    float h[D_H];
#pragma unroll
    for (int j = 0; j < D_H; ++j) h[j] = b1u[j];
    for (int k = 0; k < D_IN + D_MSG; ++k) {
        float v = in[k];
        const float* wr = W1u + (size_t)k * D_H;
#pragma unroll
        for (int j = 0; j < D_H; ++j) h[j] += v * wr[j];
    }

    float o[D_UP];
#pragma unroll
    for (int m = 0; m < D_UP; ++m) o[m] = b2u[m];
    for (int j = 0; j < D_H; ++j) {
        float r = h[j] > 0.0f ? h[j] : 0.0f;
        const float* wr = W2u + (size_t)j * D_UP;
#pragma unroll
        for (int m = 0; m < D_UP; ++m) o[m] += r * wr[m];
    }

    float4* op = (float4*)(out + (size_t)i * D_UP);
#pragma unroll
    for (int m4 = 0; m4 < D_UP / 4; ++m4)
        op[m4] = make_float4(o[4 * m4], o[4 * m4 + 1], o[4 * m4 + 2], o[4 * m4 + 3]);
}

extern "C" void kernel_launch(void* const* d_in, const int* in_sizes, int n_in,
                              void* d_out, int out_size, void* d_ws, size_t ws_size,
                              hipStream_t stream) {
    const float* x    = (const float*)d_in[0];
    // d_in[1] = degrees — unused by the reference computation
    const float* ef   = (const float*)d_in[2];
    const float* W1m  = (const float*)d_in[3];
    const float* b1m  = (const float*)d_in[4];
    const float* W2m  = (const float*)d_in[5];
    const float* b2m  = (const float*)d_in[6];
    const float* W1u  = (const float*)d_in[7];
    const float* b1u  = (const float*)d_in[8];
    const float* W2u  = (const float*)d_in[9];
    const float* b2u  = (const float*)d_in[10];
    const int*   ei   = (const int*)d_in[11];

    const int n_nodes = in_sizes[0] / D_IN;      // 50000
    const int n_edges = in_sizes[11] / 2;        // 1600000

    float* out = (float*)d_out;

    const int NB = (n_nodes + 255) / 256;        // 196 scan blocks (<=256 req'd)

    // Workspace layout:
    //   agg          : n_nodes * D_MSG  f    (6.4 MB)
    //   P1           : n_nodes * D_H    f    (12.8 MB)
    //   P2b          : n_nodes * D_H    u16  (6.4 MB)
    //   edges_sorted : n_edges          int2 (12.8 MB)
    //   deg/offs/cursor : n_nodes       i
    //   bsum/boffs   : NB               i
    float*          agg = (float*)d_ws;
    float*          P1  = agg + (size_t)n_nodes * D_MSG;
    unsigned short* P2b = (unsigned short*)(P1 + (size_t)n_nodes * D_H);
    int2* edges_sorted  = (int2*)(P2b + (size_t)n_nodes * D_H);
    int* deg    = (int*)(edges_sorted + n_edges);
    int* offs   = deg    + n_nodes;
    int* cursor = offs   + n_nodes;
    int* bsum   = cursor + n_nodes;
    int* boffs  = bsum   + NB;

    hipMemsetAsync(deg, 0, (size_t)n_nodes * sizeof(int), stream);

    {
        int blk = 256;
        int grid = (n_nodes + blk - 1) / blk;
        node_pre_kernel<<<grid, blk, 0, stream>>>(x, W1m, b1m, P1, P2b, n_nodes);
    }
    {
        int blk = 256;
        int grid = (n_edges + blk - 1) / blk;
        hist_kernel<<<grid, blk, 0, stream>>>(ei, deg, n_edges);
    }
    scan_partials_kernel<<<NB, 256, 0, stream>>>(deg, bsum, n_nodes);
    scan_blockoffs_kernel<<<1, 256, 0, stream>>>(bsum, boffs, NB);
    scan_final_kernel<<<NB, 256, 0, stream>>>(deg, boffs, offs, cursor, n_nodes);
    {
        int blk = 256;
        int grid = (n_edges + blk - 1) / blk;
        scatter_kernel<<<grid, blk, 0, stream>>>(ei, cursor, edges_sorted, n_edges);
    }
    {
        int blk = 256;
        long total = (long)n_nodes * 16;
        int grid = (int)((total + blk - 1) / blk);
        gather_kernel<<<grid, blk, 0, stream>>>(ef, W1m, W2m, P1, P2b,
                                                deg, offs, edges_sorted, agg,
                                                n_nodes);
    }
    {
        int blk = 256;
        int grid = (n_nodes + blk - 1) / blk;
        node_upd_kernel<<<grid, blk, 0, stream>>>(x, agg, deg, b2m,
                                                  W1u, b1u, W2u, b2u, out, n_nodes);
    }
}